// Round 1
// baseline (326.982 us; speedup 1.0000x reference)
//
#include <hip/hip_runtime.h>
#include <cstdint>
#include <cstddef>

// ---------------------------------------------------------------------------
// Problem: FeatureEncoder — spike-time encoding.
//   x: (64, 1, 1000, 128) fp32.  Per-batch min/max over (F,Bd) = 128000 elems.
//   norm = 8*(x-min)/(max-min)  in [0,8]
//   out[..., j] = (norm > perm[j]) ? 1.0f : 0.0f, perm = jax.random.permutation(key(1), 8)
//   out: (64, 1, 1000, 128, 8) fp32 = 65,536,000 elements, contiguous, time last.
// ---------------------------------------------------------------------------

// ===== compile-time replication of jax.random.permutation(jax.random.key(1), 8) =====
// JAX _shuffle: num_rounds = ceil(3*log(8)/log(2^32-1)) = 1 round:
//   key, subkey = split(key); bits = random_bits(subkey, 32, (8,)); sort arange by bits.
// Modern JAX (threefry_partitionable=True, default since 0.4.30):
//   split foldlike: keys[i] = Threefry2x32(key, hi=0, lo=i)  -> subkey = keys[1]
//   random_bits 32-bit, shape (8,): bits[i] = o0 ^ o1 of Threefry2x32(subkey, hi=0, lo=i)
#define JAX_PARTITIONABLE 1

struct TF2 { uint32_t a, b; };

constexpr uint32_t rotl32(uint32_t x, int d) { return (x << d) | (x >> (32 - d)); }

constexpr TF2 threefry2x32(uint32_t k0, uint32_t k1, uint32_t x0, uint32_t x1) {
  const uint32_t ks2 = k0 ^ k1 ^ 0x1BD11BDAu;
  const int R0[4] = {13, 15, 26, 6};
  const int R1[4] = {17, 29, 16, 24};
  x0 += k0; x1 += k1;
  for (int i = 0; i < 4; ++i) { x0 += x1; x1 = rotl32(x1, R0[i]); x1 ^= x0; }
  x0 += k1; x1 += ks2 + 1u;
  for (int i = 0; i < 4; ++i) { x0 += x1; x1 = rotl32(x1, R1[i]); x1 ^= x0; }
  x0 += ks2; x1 += k0 + 2u;
  for (int i = 0; i < 4; ++i) { x0 += x1; x1 = rotl32(x1, R0[i]); x1 ^= x0; }
  x0 += k0; x1 += k1 + 3u;
  for (int i = 0; i < 4; ++i) { x0 += x1; x1 = rotl32(x1, R1[i]); x1 ^= x0; }
  x0 += k1; x1 += ks2 + 4u;
  for (int i = 0; i < 4; ++i) { x0 += x1; x1 = rotl32(x1, R0[i]); x1 ^= x0; }
  x0 += ks2; x1 += k0 + 5u;
  return TF2{x0, x1};
}

struct Perm { int p[8]; };

constexpr Perm compute_perm() {
  // jax.random.key(1) -> key data (hi, lo) = (0, 1)
  uint32_t sk0 = 0, sk1 = 0;
  uint32_t bits[8] = {};
#if JAX_PARTITIONABLE
  {
    TF2 s = threefry2x32(0u, 1u, 0u, 1u);   // foldlike split, keys[1] = subkey
    sk0 = s.a; sk1 = s.b;
  }
  for (int i = 0; i < 8; ++i) {
    TF2 r = threefry2x32(sk0, sk1, 0u, (uint32_t)i);
    bits[i] = r.a ^ r.b;                     // 32-bit bits = o0 ^ o1
  }
#else
  {
    // legacy split: counts [0,1,2,3] -> lanes (0,2),(1,3); out=[a0,a1,b0,b1]; subkey=(b0,b1)
    TF2 l0 = threefry2x32(0u, 1u, 0u, 2u);
    TF2 l1 = threefry2x32(0u, 1u, 1u, 3u);
    sk0 = l0.b; sk1 = l1.b;
  }
  for (int i = 0; i < 4; ++i) {
    // legacy bits: counts iota(8) -> lanes (i, i+4); out = [a0..a3, b0..b3]
    TF2 r = threefry2x32(sk0, sk1, (uint32_t)i, (uint32_t)(i + 4));
    bits[i] = r.a; bits[i + 4] = r.b;
  }
#endif
  Perm perm = {{0, 1, 2, 3, 4, 5, 6, 7}};
  // stable ascending insertion sort by bits (matches lax.sort_key_val)
  for (int i = 1; i < 8; ++i) {
    uint32_t kb = bits[i]; int kv = perm.p[i];
    int j = i - 1;
    while (j >= 0 && bits[j] > kb) { bits[j + 1] = bits[j]; perm.p[j + 1] = perm.p[j]; --j; }
    bits[j + 1] = kb; perm.p[j + 1] = kv;
  }
  return perm;
}

constexpr Perm PERM = compute_perm();

// ===== geometry =====
static constexpr int B = 64;
static constexpr int PER_BATCH = 1000 * 128;           // 128000 floats / batch
static constexpr int PER_BATCH_F4 = PER_BATCH / 4;     // 32000 float4 / batch
static constexpr int MM_BLOCKS_PER_BATCH = 16;         // 1024 blocks total
static constexpr int MM_F4_PER_BLOCK = PER_BATCH_F4 / MM_BLOCKS_PER_BATCH;  // 2000
static constexpr int ENC_BLOCKS = (B * PER_BATCH_F4) / 256;  // 8000; 125 blocks/batch exactly

// ordered-uint encoding of finite floats: monotone increasing
__device__ inline uint32_t f2key(float f) {
  uint32_t u = __float_as_uint(f);
  return (u & 0x80000000u) ? ~u : (u | 0x80000000u);
}
__device__ inline float key2f(uint32_t k) {
  uint32_t u = (k & 0x80000000u) ? (k & 0x7FFFFFFFu) : ~k;
  return __uint_as_float(u);
}

__global__ __launch_bounds__(128) void init_keys(uint32_t* keys) {
  int i = threadIdx.x;                  // 128 threads: [2b]=min-key, [2b+1]=max-key
  keys[i] = (i & 1) ? 0u : 0xFFFFFFFFu;
}

__global__ __launch_bounds__(256) void minmax_kernel(const float4* __restrict__ in,
                                                     uint32_t* __restrict__ keys) {
  const int batch = blockIdx.x >> 4;    // 16 blocks per batch
  const int sub = blockIdx.x & 15;
  const float4* bp = in + (size_t)batch * PER_BATCH_F4;
  float mn = INFINITY, mx = -INFINITY;
  const int end = (sub + 1) * MM_F4_PER_BLOCK;
  for (int i = sub * MM_F4_PER_BLOCK + threadIdx.x; i < end; i += 256) {
    float4 v = bp[i];
    mn = fminf(mn, fminf(fminf(v.x, v.y), fminf(v.z, v.w)));
    mx = fmaxf(mx, fmaxf(fmaxf(v.x, v.y), fmaxf(v.z, v.w)));
  }
  #pragma unroll
  for (int off = 32; off > 0; off >>= 1) {
    mn = fminf(mn, __shfl_down(mn, off));
    mx = fmaxf(mx, __shfl_down(mx, off));
  }
  __shared__ float smn[4], smx[4];
  const int wave = threadIdx.x >> 6, lane = threadIdx.x & 63;
  if (lane == 0) { smn[wave] = mn; smx[wave] = mx; }
  __syncthreads();
  if (threadIdx.x == 0) {
    mn = fminf(fminf(smn[0], smn[1]), fminf(smn[2], smn[3]));
    mx = fmaxf(fmaxf(smx[0], smx[1]), fmaxf(smx[2], smx[3]));
    atomicMin(&keys[2 * batch], f2key(mn));
    atomicMax(&keys[2 * batch + 1], f2key(mx));
  }
}

__global__ __launch_bounds__(256) void encode_kernel(const float4* __restrict__ in,
                                                     float4* __restrict__ out,
                                                     const uint32_t* __restrict__ keys) {
  const int t4 = blockIdx.x * 256 + threadIdx.x;   // float4 index over input
  const int batch = blockIdx.x / 125;              // 125 blocks per batch (exact)
  const float mn = key2f(keys[2 * batch]);
  const float mx = key2f(keys[2 * batch + 1]);
  const float rng = mx - mn;

  const float4 x = in[t4];
  // EXACT replication of ref arithmetic: (8*(x-mn)) / rng, IEEE fp32 division.
  float n[4];
  n[0] = (8.0f * (x.x - mn)) / rng;
  n[1] = (8.0f * (x.y - mn)) / rng;
  n[2] = (8.0f * (x.z - mn)) / rng;
  n[3] = (8.0f * (x.w - mn)) / rng;

  constexpr float TH[8] = {
    (float)PERM.p[0], (float)PERM.p[1], (float)PERM.p[2], (float)PERM.p[3],
    (float)PERM.p[4], (float)PERM.p[5], (float)PERM.p[6], (float)PERM.p[7]
  };

  float4 o[8];
  #pragma unroll
  for (int e = 0; e < 4; ++e) {
    o[2 * e + 0].x = n[e] > TH[0] ? 1.0f : 0.0f;
    o[2 * e + 0].y = n[e] > TH[1] ? 1.0f : 0.0f;
    o[2 * e + 0].z = n[e] > TH[2] ? 1.0f : 0.0f;
    o[2 * e + 0].w = n[e] > TH[3] ? 1.0f : 0.0f;
    o[2 * e + 1].x = n[e] > TH[4] ? 1.0f : 0.0f;
    o[2 * e + 1].y = n[e] > TH[5] ? 1.0f : 0.0f;
    o[2 * e + 1].z = n[e] > TH[6] ? 1.0f : 0.0f;
    o[2 * e + 1].w = n[e] > TH[7] ? 1.0f : 0.0f;
  }

  float4* op = out + (size_t)t4 * 8;               // 32 output floats per input float4
  #pragma unroll
  for (int k = 0; k < 8; ++k) op[k] = o[k];
}

extern "C" void kernel_launch(void* const* d_in, const int* in_sizes, int n_in,
                              void* d_out, int out_size, void* d_ws, size_t ws_size,
                              hipStream_t stream) {
  const float4* in = (const float4*)d_in[0];
  float4* out = (float4*)d_out;
  uint32_t* keys = (uint32_t*)d_ws;

  hipLaunchKernelGGL(init_keys, dim3(1), dim3(128), 0, stream, keys);
  hipLaunchKernelGGL(minmax_kernel, dim3(B * MM_BLOCKS_PER_BATCH), dim3(256), 0, stream,
                     in, keys);
  hipLaunchKernelGGL(encode_kernel, dim3(ENC_BLOCKS), dim3(256), 0, stream,
                     in, out, keys);
}

// Round 3
// 284.987 us; speedup vs baseline: 1.1474x; 1.1474x over previous
//
#include <hip/hip_runtime.h>
#include <cstdint>
#include <cstddef>

// ---------------------------------------------------------------------------
// FeatureEncoder — spike-time encoding.
//   x: (64, 1, 1000, 128) fp32.  Per-batch min/max over (F,Bd) = 128000 elems.
//   norm = (8*(x-min))/(max-min)
//   out[..., j] = (norm > perm[j]) ? 1 : 0, perm = jax.random.permutation(key(1), 8)
//   out: (64, 1, 1000, 128, 8) fp32, time-axis contiguous.
// R1 -> R2: encode writes were 128B-strided per lane (0.9 TB/s). Restructure so
// each store instruction writes lane-contiguous float4s. R2 -> R3: use native
// clang vector type for __builtin_nontemporal_store (HIP_vector_type rejected).
// ---------------------------------------------------------------------------

typedef float f32x4 __attribute__((ext_vector_type(4)));

// ===== compile-time jax.random.permutation(jax.random.key(1), 8) =====
// Verified exact in R1 (absmax 0): partitionable split + 32-bit fold bits,
// stable sort of arange by bits.
struct TF2 { uint32_t a, b; };

constexpr uint32_t rotl32(uint32_t x, int d) { return (x << d) | (x >> (32 - d)); }

constexpr TF2 threefry2x32(uint32_t k0, uint32_t k1, uint32_t x0, uint32_t x1) {
  const uint32_t ks2 = k0 ^ k1 ^ 0x1BD11BDAu;
  const int R0[4] = {13, 15, 26, 6};
  const int R1[4] = {17, 29, 16, 24};
  x0 += k0; x1 += k1;
  for (int i = 0; i < 4; ++i) { x0 += x1; x1 = rotl32(x1, R0[i]); x1 ^= x0; }
  x0 += k1; x1 += ks2 + 1u;
  for (int i = 0; i < 4; ++i) { x0 += x1; x1 = rotl32(x1, R1[i]); x1 ^= x0; }
  x0 += ks2; x1 += k0 + 2u;
  for (int i = 0; i < 4; ++i) { x0 += x1; x1 = rotl32(x1, R0[i]); x1 ^= x0; }
  x0 += k0; x1 += k1 + 3u;
  for (int i = 0; i < 4; ++i) { x0 += x1; x1 = rotl32(x1, R1[i]); x1 ^= x0; }
  x0 += k1; x1 += ks2 + 4u;
  for (int i = 0; i < 4; ++i) { x0 += x1; x1 = rotl32(x1, R0[i]); x1 ^= x0; }
  x0 += ks2; x1 += k0 + 5u;
  return TF2{x0, x1};
}

struct Perm { int p[8]; };

constexpr Perm compute_perm() {
  TF2 s = threefry2x32(0u, 1u, 0u, 1u);      // foldlike split -> subkey
  uint32_t sk0 = s.a, sk1 = s.b;
  uint32_t bits[8] = {};
  for (int i = 0; i < 8; ++i) {
    TF2 r = threefry2x32(sk0, sk1, 0u, (uint32_t)i);
    bits[i] = r.a ^ r.b;
  }
  Perm perm = {{0, 1, 2, 3, 4, 5, 6, 7}};
  for (int i = 1; i < 8; ++i) {
    uint32_t kb = bits[i]; int kv = perm.p[i];
    int j = i - 1;
    while (j >= 0 && bits[j] > kb) { bits[j + 1] = bits[j]; perm.p[j + 1] = perm.p[j]; --j; }
    bits[j + 1] = kb; perm.p[j + 1] = kv;
  }
  return perm;
}

constexpr Perm PERM = compute_perm();

// ===== geometry =====
static constexpr int B = 64;
static constexpr int PER_BATCH = 1000 * 128;            // 128000 floats / batch
static constexpr int PER_BATCH_F4 = PER_BATCH / 4;      // 32000 float4 / batch
static constexpr int MM_BLOCKS_PER_BATCH = 16;          // 1024 blocks total
static constexpr int MM_F4_PER_BLOCK = PER_BATCH_F4 / MM_BLOCKS_PER_BATCH;  // 2000

// encode: out float4 count = 64*128000*8/4 = 16,384,000.
// Each block: 256 threads x 8 stores = 2048 out-float4 (32 KB).
static constexpr int ENC_OUT4_PER_BLOCK = 2048;
static constexpr int ENC_BLOCKS = 16384000 / ENC_OUT4_PER_BLOCK;  // 8000
static constexpr int ENC_BLOCKS_PER_BATCH = 125;                  // exact: 256000/2048

// ordered-uint encoding of finite floats: monotone increasing
__device__ inline uint32_t f2key(float f) {
  uint32_t u = __float_as_uint(f);
  return (u & 0x80000000u) ? ~u : (u | 0x80000000u);
}
__device__ inline float key2f(uint32_t k) {
  uint32_t u = (k & 0x80000000u) ? (k & 0x7FFFFFFFu) : ~k;
  return __uint_as_float(u);
}

__global__ __launch_bounds__(128) void init_keys(uint32_t* keys) {
  int i = threadIdx.x;
  keys[i] = (i & 1) ? 0u : 0xFFFFFFFFu;
}

__global__ __launch_bounds__(256) void minmax_kernel(const float4* __restrict__ in,
                                                     uint32_t* __restrict__ keys) {
  const int batch = blockIdx.x >> 4;
  const int sub = blockIdx.x & 15;
  const float4* bp = in + (size_t)batch * PER_BATCH_F4;
  float mn = INFINITY, mx = -INFINITY;
  const int end = (sub + 1) * MM_F4_PER_BLOCK;
  for (int i = sub * MM_F4_PER_BLOCK + threadIdx.x; i < end; i += 256) {
    float4 v = bp[i];
    mn = fminf(mn, fminf(fminf(v.x, v.y), fminf(v.z, v.w)));
    mx = fmaxf(mx, fmaxf(fmaxf(v.x, v.y), fmaxf(v.z, v.w)));
  }
  #pragma unroll
  for (int off = 32; off > 0; off >>= 1) {
    mn = fminf(mn, __shfl_down(mn, off));
    mx = fmaxf(mx, __shfl_down(mx, off));
  }
  __shared__ float smn[4], smx[4];
  const int wave = threadIdx.x >> 6, lane = threadIdx.x & 63;
  if (lane == 0) { smn[wave] = mn; smx[wave] = mx; }
  __syncthreads();
  if (threadIdx.x == 0) {
    mn = fminf(fminf(smn[0], smn[1]), fminf(smn[2], smn[3]));
    mx = fmaxf(fmaxf(smx[0], smx[1]), fmaxf(smx[2], smx[3]));
    atomicMin(&keys[2 * batch], f2key(mn));
    atomicMax(&keys[2 * batch + 1], f2key(mx));
  }
}

__global__ __launch_bounds__(256) void encode_kernel(const float* __restrict__ in,
                                                     f32x4* __restrict__ out,
                                                     const uint32_t* __restrict__ keys) {
  const int batch = blockIdx.x / ENC_BLOCKS_PER_BATCH;   // 125 blocks/batch exact
  const float mn = key2f(keys[2 * batch]);
  const float mx = key2f(keys[2 * batch + 1]);
  const float rng = mx - mn;

  // thread parity fixed across all 8 stores (stride 256 is even):
  // even out4 -> time slots 0..3, odd out4 -> time slots 4..7.
  const int p = (threadIdx.x & 1) * 4;
  const float th0 = (float)PERM.p[p + 0];
  const float th1 = (float)PERM.p[p + 1];
  const float th2 = (float)PERM.p[p + 2];
  const float th3 = (float)PERM.p[p + 3];

  const int out4_base = blockIdx.x * ENC_OUT4_PER_BLOCK + threadIdx.x;
  #pragma unroll
  for (int k = 0; k < 8; ++k) {
    const int o4 = out4_base + k * 256;          // lane-contiguous per instruction
    const float x = in[o4 >> 1];                 // 2 lanes share 1 elem (coalesced)
    // EXACT ref arithmetic: (8*(x-mn)) / rng, IEEE fp32 division.
    const float n = (8.0f * (x - mn)) / rng;
    f32x4 o;
    o.x = n > th0 ? 1.0f : 0.0f;
    o.y = n > th1 ? 1.0f : 0.0f;
    o.z = n > th2 ? 1.0f : 0.0f;
    o.w = n > th3 ? 1.0f : 0.0f;
    __builtin_nontemporal_store(o, &out[o4]);    // no reuse; skip L2 pollution
  }
}

extern "C" void kernel_launch(void* const* d_in, const int* in_sizes, int n_in,
                              void* d_out, int out_size, void* d_ws, size_t ws_size,
                              hipStream_t stream) {
  const float* in = (const float*)d_in[0];
  f32x4* out = (f32x4*)d_out;
  uint32_t* keys = (uint32_t*)d_ws;

  hipLaunchKernelGGL(init_keys, dim3(1), dim3(128), 0, stream, keys);
  hipLaunchKernelGGL(minmax_kernel, dim3(B * MM_BLOCKS_PER_BATCH), dim3(256), 0, stream,
                     (const float4*)in, keys);
  hipLaunchKernelGGL(encode_kernel, dim3(ENC_BLOCKS), dim3(256), 0, stream,
                     in, out, keys);
}